// Round 1
// baseline (899.389 us; speedup 1.0000x reference)
//
#include <hip/hip_runtime.h>
#include <stdint.h>

typedef __attribute__((ext_vector_type(8))) short short8;
typedef __attribute__((ext_vector_type(4))) short short4v;
typedef __attribute__((ext_vector_type(4))) float f32x4;

#define AS1 __attribute__((address_space(1)))
#define AS3 __attribute__((address_space(3)))

// ---------------- LDS layout (bytes) ----------------
// X   : 80 rows * 1024 B (bf16, XOR-swizzled rows)           [0, 81920)
// U   : union { wb0 16K | wb1 16K | T 80*512 | VT 256*208 }  [81920, 135168)
// BigW: 80*208 bf16 (stride 104 elems, conflict-free)        [135168, 151808)
// S   : 8*81 f32 scores                                      [151808, 154400)
// mask/a/b/gates                                             [154400, 155400)
#define SM_X     0
#define SM_U     81920
#define SM_WB1   (SM_U + 16384)
#define SM_BW    135168
#define SM_S     151808
#define SM_MASK  154400
#define SM_A     154728
#define SM_B     155048
#define SM_G     155368
#define SM_TOT   155400

static __device__ __forceinline__ short f2bf(float f){
  unsigned u = __builtin_bit_cast(unsigned, f);
  u += 0x7FFFu + ((u >> 16) & 1u);           // RNE
  return (short)(u >> 16);
}
static __device__ __forceinline__ float wred64(float v){
  #pragma unroll
  for (int o = 1; o < 64; o <<= 1) v += __shfl_xor(v, o, 64);
  return v;
}
// B-fragment-sequential packed weight layout (bf16 elements):
// block = (kstep = k>>5, p = n>>8, frag = (n>>4)&15) of 512 elems; within block
// elem = ((kg= (k>>3)&3)*16 + (n&15))*8 + (k&7)  ==> lane l reads bytes l*16..l*16+15
static __device__ __forceinline__ size_t prep_off(int k, int n){
  return ((size_t)(((k >> 5) * 2 + (n >> 8)) * 16 + ((n >> 4) & 15))) * 512
       + (size_t)((((k >> 3) & 3) * 16 + (n & 15)) * 8 + (k & 7));
}

// =====================================================================
// prep kernel: M = Wq*Wk^T (packed bf16), Wv packed bf16, u=Wq@bk, w=Wk@bq, c=bq.bk
// =====================================================================
__global__ __launch_bounds__(256) void vortex_prep(
    const float* __restrict__ Wq, const float* __restrict__ bq,
    const float* __restrict__ Wk, const float* __restrict__ bk,
    const float* __restrict__ Wv,
    short* __restrict__ Mp, short* __restrict__ Vp,
    float* __restrict__ uvec, float* __restrict__ wvec, float* __restrict__ cval)
{
  const int blk = blockIdx.x, tid = threadIdx.x;
  if (blk < 256){
    // 1024 tiles of 16x16, one per wave: M[d1][d2] = sum_j Wq[d1][j]*Wk[d2][j]
    const int wv = tid >> 6, lane = tid & 63;
    const int tile = blk * 4 + wv, ti = tile >> 5, tj = tile & 31;
    const int r = lane & 15, g = lane >> 4;
    f32x4 acc = {0.f, 0.f, 0.f, 0.f};
    for (int k0 = 0; k0 < 512; k0 += 32){
      const float* ap = Wq + (ti*16 + r)*512 + k0 + g*8;
      const float* bp = Wk + (tj*16 + r)*512 + k0 + g*8;
      f32x4 a0 = *(const f32x4*)ap, a1 = *(const f32x4*)(ap+4);
      f32x4 b0 = *(const f32x4*)bp, b1 = *(const f32x4*)(bp+4);
      short8 av, bv8;
      av[0]=f2bf(a0[0]); av[1]=f2bf(a0[1]); av[2]=f2bf(a0[2]); av[3]=f2bf(a0[3]);
      av[4]=f2bf(a1[0]); av[5]=f2bf(a1[1]); av[6]=f2bf(a1[2]); av[7]=f2bf(a1[3]);
      bv8[0]=f2bf(b0[0]); bv8[1]=f2bf(b0[1]); bv8[2]=f2bf(b0[2]); bv8[3]=f2bf(b0[3]);
      bv8[4]=f2bf(b1[0]); bv8[5]=f2bf(b1[1]); bv8[6]=f2bf(b1[2]); bv8[7]=f2bf(b1[3]);
      acc = __builtin_amdgcn_mfma_f32_16x16x32_bf16(av, bv8, acc, 0, 0, 0);
    }
    #pragma unroll
    for (int rr = 0; rr < 4; ++rr){
      int d1 = ti*16 + g*4 + rr, d2 = tj*16 + r;   // C/D: col=lane&15, row=(lane>>4)*4+reg
      Mp[prep_off(d1, d2)] = f2bf(acc[rr]);
    }
  } else if (blk < 320){
    // pack Wv (fp32 row-major) -> bf16 B-ready layout
    int base = ((blk - 256) * 256 + tid) * 16;
    #pragma unroll
    for (int e = 0; e < 16; ++e){
      int idx = base + e;
      Vp[prep_off(idx >> 9, idx & 511)] = f2bf(Wv[idx]);
    }
  } else {
    for (int d = tid; d < 512; d += 256){
      float su = 0.f, sw = 0.f;
      for (int j = 0; j < 512; ++j){
        su = fmaf(Wq[d*512 + j], bk[j], su);
        sw = fmaf(Wk[d*512 + j], bq[j], sw);
      }
      uvec[d] = su; wvec[d] = sw;
    }
    if (tid == 0){
      float s = 0.f;
      for (int j = 0; j < 512; ++j) s = fmaf(bq[j], bk[j], s);
      *cval = s;
    }
  }
}

// =====================================================================
// main fused kernel
// =====================================================================
static __device__ __forceinline__ void stage2(const char* g, char* l){
  __builtin_amdgcn_global_load_lds((const AS1 unsigned*)g,        (AS3 unsigned*)l,        16, 0, 0);
  __builtin_amdgcn_global_load_lds((const AS1 unsigned*)(g+1024), (AS3 unsigned*)(l+1024), 16, 0, 0);
}

// one 80x256 GEMM pass: acc[5][2] += X(80x512 bf16 LDS) @ prep[:, p*256:p*256+256]
static __device__ __forceinline__ void gemm_kloop(const char* prep, int p, char* sm,
                                                  int w, int lane, f32x4 (&acc)[5][2])
{
  const int l15 = lane & 15, lg = lane >> 4;
  const int goff = w*2048 + lane*16;
  char* wb0 = sm + SM_U;
  char* wb1 = sm + SM_WB1;
  stage2(prep + (size_t)p*16384 + goff, wb0 + w*2048);
  __syncthreads();
  for (int ks = 0; ks < 16; ++ks){
    char* rb = (ks & 1) ? wb1 : wb0;
    if (ks < 15){
      char* nb = (ks & 1) ? wb0 : wb1;
      stage2(prep + (size_t)((ks+1)*2 + p)*16384 + goff, nb + w*2048);
    }
    short8 af[5], bfr[2];
    #pragma unroll
    for (int mf = 0; mf < 5; ++mf){
      const int row = mf*16 + l15;
      af[mf] = *(const short8*)(sm + (row << 10) + (((ks << 6) | (lg << 4)) ^ ((row & 7) << 4)));
    }
    bfr[0] = *(const short8*)(rb + (2*w  )*1024 + lane*16);
    bfr[1] = *(const short8*)(rb + (2*w+1)*1024 + lane*16);
    #pragma unroll
    for (int mf = 0; mf < 5; ++mf){
      acc[mf][0] = __builtin_amdgcn_mfma_f32_16x16x32_bf16(af[mf], bfr[0], acc[mf][0], 0,0,0);
      acc[mf][1] = __builtin_amdgcn_mfma_f32_16x16x32_bf16(af[mf], bfr[1], acc[mf][1], 0,0,0);
    }
    __syncthreads();
  }
}

__global__ __launch_bounds__(512, 2) void vortex_main(
    const float* __restrict__ nf, const float* __restrict__ pos,
    const float* __restrict__ bv, const float* __restrict__ Wg, const float* __restrict__ bgp,
    const short* __restrict__ Mp, const short* __restrict__ Vp,
    const float* __restrict__ uvec, const float* __restrict__ wvec, const float* __restrict__ cptr,
    float* __restrict__ out)
{
  __shared__ __align__(16) char sm[SM_TOT];
  const int tid = threadIdx.x;
  const int w = tid >> 6, lane = tid & 63;
  const int l15 = lane & 15, lg = lane >> 4;
  const int wg = blockIdx.x;

  short8 creg;   // this wave's central row (batch w), bf16
  // ---------------- setup: X -> LDS (bf16, swizzled), dots, gate, mask ----------------
  {
    const int col0 = lane * 8;
    f32x4 u0 = *(const f32x4*)(uvec + col0), u1 = *(const f32x4*)(uvec + col0 + 4);
    f32x4 v0 = *(const f32x4*)(wvec + col0), v1 = *(const f32x4*)(wvec + col0 + 4);
    f32x4 g0 = *(const f32x4*)(Wg   + col0), g1 = *(const f32x4*)(Wg   + col0 + 4);
    const size_t gb = ((size_t)wg*8 + w) * 9 * 512;
    for (int rl = 0; rl < 9; ++rl){
      f32x4 n0 = *(const f32x4*)(nf + gb + rl*512 + col0);
      f32x4 n1 = *(const f32x4*)(nf + gb + rl*512 + col0 + 4);
      f32x4 p0 = *(const f32x4*)(pos + rl*512 + col0);
      f32x4 p1 = *(const f32x4*)(pos + rl*512 + col0 + 4);
      f32x4 x0 = n0 + p0, x1 = n1 + p1;
      short8 xb;
      xb[0]=f2bf(x0[0]); xb[1]=f2bf(x0[1]); xb[2]=f2bf(x0[2]); xb[3]=f2bf(x0[3]);
      xb[4]=f2bf(x1[0]); xb[5]=f2bf(x1[1]); xb[6]=f2bf(x1[2]); xb[7]=f2bf(x1[3]);
      const int row = w*9 + rl;
      *(short8*)(sm + (row << 10) + ((lane << 4) ^ ((row & 7) << 4))) = xb;
      float pa = x0[0]*u0[0]+x0[1]*u0[1]+x0[2]*u0[2]+x0[3]*u0[3]
               + x1[0]*u1[0]+x1[1]*u1[1]+x1[2]*u1[2]+x1[3]*u1[3];
      float pb = x0[0]*v0[0]+x0[1]*v0[1]+x0[2]*v0[2]+x0[3]*v0[3]
               + x1[0]*v1[0]+x1[1]*v1[1]+x1[2]*v1[2]+x1[3]*v1[3];
      pa = wred64(pa); pb = wred64(pb);
      if (lane == 0){
        ((float*)(sm + SM_A))[row] = pa;
        ((float*)(sm + SM_B))[row] = pb;
      }
      if (rl == 8){
        short8 cb;
        cb[0]=f2bf(n0[0]); cb[1]=f2bf(n0[1]); cb[2]=f2bf(n0[2]); cb[3]=f2bf(n0[3]);
        cb[4]=f2bf(n1[0]); cb[5]=f2bf(n1[1]); cb[6]=f2bf(n1[2]); cb[7]=f2bf(n1[3]);
        creg = cb;
        float pg = n0[0]*g0[0]+n0[1]*g0[1]+n0[2]*g0[2]+n0[3]*g0[3]
                 + n1[0]*g1[0]+n1[1]*g1[1]+n1[2]*g1[2]+n1[3]*g1[3];
        pg = wred64(pg);
        if (lane == 0){
          float z = pg + bgp[0];
          ((float*)(sm + SM_G))[w] = 1.f / (1.f + __expf(-z));
        }
      }
    }
    { // zero pad row (72+w)
      const int row = 72 + w;
      short8 z = {0,0,0,0,0,0,0,0};
      *(short8*)(sm + (row << 10) + ((lane << 4) ^ ((row & 7) << 4))) = z;
    }
    for (int t = tid; t < 1040; t += 512){   // zero BigW (80*208 B)
      f32x4 z = {0.f,0.f,0.f,0.f};
      *(f32x4*)(sm + SM_BW + t*16) = z;
    }
    if (tid < 81){
      int n = tid / 9, m = tid - (tid/9)*9;
      bool edge = ((n%3)==0 && (m%3)==1) || ((n%3)==1 && (m%3)==0)
               || (n==2 && m==5) || (n==5 && m==2);
      float mv = (n==8 || m==8) ? 1.5f : (edge ? 2.0f : 1.0f);
      ((float*)(sm + SM_MASK))[tid] = mv;
    }
  }
  __syncthreads();

  // score tile assignment (13 tiles covering block-diag of 80x80)
  const int mi0 = (w + 1) / 3,  nj0 = w - 2*mi0;
  const int mi1 = (w + 9) / 3,  nj1 = (w + 8) - 2*mi1;

  f32x4 sacc0 = {0.f,0.f,0.f,0.f}, sacc1 = {0.f,0.f,0.f,0.f};

  // ---------------- G1: t = X@M (2 passes of 256 cols) + score MFMA ----------------
  for (int p = 0; p < 2; ++p){
    f32x4 tacc[5][2];
    #pragma unroll
    for (int mf = 0; mf < 5; ++mf){
      tacc[mf][0] = (f32x4){0.f,0.f,0.f,0.f};
      tacc[mf][1] = (f32x4){0.f,0.f,0.f,0.f};
    }
    gemm_kloop((const char*)Mp, p, sm, w, lane, tacc);
    // write T (row-major [80][256] bf16, swizzled)
    #pragma unroll
    for (int mf = 0; mf < 5; ++mf)
      #pragma unroll
      for (int nfi = 0; nfi < 2; ++nfi){
        const int col = w*32 + nfi*16 + l15;
        #pragma unroll
        for (int r = 0; r < 4; ++r){
          const int row = mf*16 + lg*4 + r;
          *(short*)(sm + SM_U + (row << 9) + ((col*2) ^ ((row & 7) << 4))) = f2bf(tacc[mf][nfi][r]);
        }
      }
    __syncthreads();
    // S^T tiles: D[m][n] = sum_d2 X[m][d2] * T[n][d2]
    #pragma unroll
    for (int ks = 0; ks < 8; ++ks){
      const int ar = mi0*16 + l15;
      short8 a = *(const short8*)(sm + (ar<<10) + (((p<<9)|(ks<<6)|(lg<<4)) ^ ((ar&7)<<4)));
      const int br = nj0*16 + l15;
      short8 b = *(const short8*)(sm + SM_U + (br<<9) + (((ks<<6)|(lg<<4)) ^ ((br&7)<<4)));
      sacc0 = __builtin_amdgcn_mfma_f32_16x16x32_bf16(a, b, sacc0, 0,0,0);
    }
    if (w < 5){
      #pragma unroll
      for (int ks = 0; ks < 8; ++ks){
        const int ar = mi1*16 + l15;
        short8 a = *(const short8*)(sm + (ar<<10) + (((p<<9)|(ks<<6)|(lg<<4)) ^ ((ar&7)<<4)));
        const int br = nj1*16 + l15;
        short8 b = *(const short8*)(sm + SM_U + (br<<9) + (((ks<<6)|(lg<<4)) ^ ((br&7)<<4)));
        sacc1 = __builtin_amdgcn_mfma_f32_16x16x32_bf16(a, b, sacc1, 0,0,0);
      }
    }
    __syncthreads();
  }

  // ---------------- extract block-diag scores ----------------
  {
    #pragma unroll
    for (int r = 0; r < 4; ++r){
      const int m = mi0*16 + lg*4 + r, n = nj0*16 + l15;
      if (m < 72 && n < 72){
        const int bm = (m*57)>>9, bn = (n*57)>>9;
        if (bm == bn)
          ((float*)(sm + SM_S))[bm*81 + (n - bn*9)*9 + (m - bm*9)] = sacc0[r];
      }
    }
    if (w < 5){
      #pragma unroll
      for (int r = 0; r < 4; ++r){
        const int m = mi1*16 + lg*4 + r, n = nj1*16 + l15;
        if (m < 72 && n < 72){
          const int bm = (m*57)>>9, bn = (n*57)>>9;
          if (bm == bn)
            ((float*)(sm + SM_S))[bm*81 + (n - bn*9)*9 + (m - bm*9)] = sacc1[r];
        }
      }
    }
  }
  __syncthreads();

  // ---------------- softmax -> BigW (w*(1-g) in diag block, g at col 80+b) ----------------
  if (tid < 72){
    const int b = tid / 9, np = tid - b*9;
    const float g  = ((float*)(sm + SM_G))[b];
    const float an = ((float*)(sm + SM_A))[b*9 + np];
    const float cv = cptr[0];
    const float scl = 0.04419417382415922f;   // 1/sqrt(512)
    float vals[9]; float mx = -1e30f;
    #pragma unroll
    for (int m = 0; m < 9; ++m){
      float s = (((float*)(sm + SM_S))[b*81 + np*9 + m] + an
                 + ((float*)(sm + SM_B))[b*9 + m] + cv)
              * scl * ((float*)(sm + SM_MASK))[np*9 + m];
      vals[m] = s; mx = fmaxf(mx, s);
    }
    float sum = 0.f;
    #pragma unroll
    for (int m = 0; m < 9; ++m){ vals[m] = __expf(vals[m] - mx); sum += vals[m]; }
    const float wsc = (1.f - g) / sum;
    const int rowg = b*9 + np;
    #pragma unroll
    for (int m = 0; m < 9; ++m)
      *(short*)(sm + SM_BW + rowg*208 + (b*9 + m)*2) = f2bf(vals[m]*wsc);
    *(short*)(sm + SM_BW + rowg*208 + (80 + b)*2) = f2bf(g);
  }
  __syncthreads();

  // ---------------- G2: V = X@Wv -> V^T LDS; out = BigW @ V (+ (1-g)*bv) ----------------
  for (int p = 0; p < 2; ++p){
    f32x4 vacc[5][2];
    #pragma unroll
    for (int mf = 0; mf < 5; ++mf){
      vacc[mf][0] = (f32x4){0.f,0.f,0.f,0.f};
      vacc[mf][1] = (f32x4){0.f,0.f,0.f,0.f};
    }
    gemm_kloop((const char*)Vp, p, sm, w, lane, vacc);
    // V^T: [256][104] bf16 (stride 208 B = 13 granules -> conflict-free)
    #pragma unroll
    for (int mf = 0; mf < 5; ++mf)
      #pragma unroll
      for (int nfi = 0; nfi < 2; ++nfi){
        const int d  = w*32 + nfi*16 + l15;      // chunk-local col of V
        const int m0 = mf*16 + lg*4;
        short4v pk;
        pk[0]=f2bf(vacc[mf][nfi][0]); pk[1]=f2bf(vacc[mf][nfi][1]);
        pk[2]=f2bf(vacc[mf][nfi][2]); pk[3]=f2bf(vacc[mf][nfi][3]);
        *(short4v*)(sm + SM_U + d*208 + m0*2) = pk;
      }
    #pragma unroll
    for (int j = 0; j < 8; ++j){                 // central rows 80..87
      const int d = lane*8 + j;
      if ((d >> 8) == p)
        *(short*)(sm + SM_U + (d & 255)*208 + (80 + w)*2) = creg[j];
    }
    __syncthreads();
    // out chunk = BigW(80x96) @ V(96x256)
    f32x4 oacc[5][2];
    #pragma unroll
    for (int mf = 0; mf < 5; ++mf){
      oacc[mf][0] = (f32x4){0.f,0.f,0.f,0.f};
      oacc[mf][1] = (f32x4){0.f,0.f,0.f,0.f};
    }
    #pragma unroll
    for (int ks = 0; ks < 3; ++ks){
      short8 aw[5], bw0, bw1;
      #pragma unroll
      for (int mf = 0; mf < 5; ++mf){
        const int n = mf*16 + l15;
        aw[mf] = *(const short8*)(sm + SM_BW + n*208 + ks*64 + lg*16);
      }
      bw0 = *(const short8*)(sm + SM_U + (w*32      + l15)*208 + ks*64 + lg*16);
      bw1 = *(const short8*)(sm + SM_U + (w*32 + 16 + l15)*208 + ks*64 + lg*16);
      #pragma unroll
      for (int mf = 0; mf < 5; ++mf){
        oacc[mf][0] = __builtin_amdgcn_mfma_f32_16x16x32_bf16(aw[mf], bw0, oacc[mf][0], 0,0,0);
        oacc[mf][1] = __builtin_amdgcn_mfma_f32_16x16x32_bf16(aw[mf], bw1, oacc[mf][1], 0,0,0);
      }
    }
    // epilogue + store
    #pragma unroll
    for (int nfi = 0; nfi < 2; ++nfi){
      const int d = p*256 + w*32 + nfi*16 + l15;
      const float bvd = bv[d];
      #pragma unroll
      for (int mf = 0; mf < 5; ++mf)
        #pragma unroll
        for (int r = 0; r < 4; ++r){
          const int n = mf*16 + lg*4 + r;
          if (n < 72){
            const int b = (n*57)>>9;
            const float g = ((float*)(sm + SM_G))[b];
            out[((size_t)wg*72 + n)*512 + d] = oacc[mf][nfi][r] + (1.f - g)*bvd;
          }
        }
    }
    __syncthreads();
  }
}

// =====================================================================
extern "C" void kernel_launch(void* const* d_in, const int* in_sizes, int n_in,
                              void* d_out, int out_size, void* d_ws, size_t ws_size,
                              hipStream_t stream)
{
  const float* nf  = (const float*)d_in[0];
  const float* pos = (const float*)d_in[1];
  const float* Wq  = (const float*)d_in[2];
  const float* bq  = (const float*)d_in[3];
  const float* Wk  = (const float*)d_in[4];
  const float* bk  = (const float*)d_in[5];
  const float* Wv  = (const float*)d_in[6];
  const float* bv  = (const float*)d_in[7];
  const float* Wg  = (const float*)d_in[8];
  const float* bg  = (const float*)d_in[9];
  float* out = (float*)d_out;
  char* ws = (char*)d_ws;
  // ws: Mprep 512K | Wvprep 512K | u 2K | w 2K | c 4B   (needs ~1.004 MB)
  short* Mp   = (short*)(ws);
  short* Vp   = (short*)(ws + 524288);
  float* uvec = (float*)(ws + 1048576);
  float* wvec = (float*)(ws + 1050624);
  float* cval = (float*)(ws + 1052672);
  if (ws_size < 1052676) return;

  const int B = in_sizes[0] / (9 * 512);
  vortex_prep<<<321, 256, 0, stream>>>(Wq, bq, Wk, bk, Wv, Mp, Vp, uvec, wvec, cval);
  vortex_main<<<B/8, 512, 0, stream>>>(nf, pos, bv, Wg, bg, Mp, Vp, uvec, wvec, cval, out);
}

// Round 2
// 778.633 us; speedup vs baseline: 1.1551x; 1.1551x over previous
//
#include <hip/hip_runtime.h>
#include <stdint.h>

typedef __attribute__((ext_vector_type(8))) short short8;
typedef __attribute__((ext_vector_type(4))) short short4v;
typedef __attribute__((ext_vector_type(4))) float f32x4;

// ---------------- LDS layout (bytes) ----------------
// X   : 80 rows * 1024 B (bf16, XOR-swizzled rows)           [0, 81920)
// U   : union { T 80*512 | VT 256*208 }                      [81920, 135168)
// BigW: 80*208 bf16 (stride 104 elems, conflict-free)        [135168, 151808)
// S   : 8*81 f32 scores                                      [151808, 154400)
// mask/a/b/gates                                             [154400, 155400)
#define SM_X     0
#define SM_U     81920
#define SM_BW    135168
#define SM_S     151808
#define SM_MASK  154400
#define SM_A     154728
#define SM_B     155048
#define SM_G     155368
#define SM_TOT   155400

static __device__ __forceinline__ short f2bf(float f){
  unsigned u = __builtin_bit_cast(unsigned, f);
  u += 0x7FFFu + ((u >> 16) & 1u);           // RNE
  return (short)(u >> 16);
}
static __device__ __forceinline__ float wred64(float v){
  #pragma unroll
  for (int o = 1; o < 64; o <<= 1) v += __shfl_xor(v, o, 64);
  return v;
}
static __device__ __forceinline__ float dot8(f32x4 a0, f32x4 a1, f32x4 b0, f32x4 b1){
  return a0[0]*b0[0]+a0[1]*b0[1]+a0[2]*b0[2]+a0[3]*b0[3]
       + a1[0]*b1[0]+a1[1]*b1[1]+a1[2]*b1[2]+a1[3]*b1[3];
}
// B-fragment-sequential packed weight layout (bf16 elements):
// block = (kstep = k>>5, p = n>>8, frag = (n>>4)&15) of 512 elems; within block
// elem = ((kg=(k>>3)&3)*16 + (n&15))*8 + (k&7)  ==> lane l reads bytes l*16..l*16+15
static __device__ __forceinline__ size_t prep_off(int k, int n){
  return ((size_t)(((k >> 5) * 2 + (n >> 8)) * 16 + ((n >> 4) & 15))) * 512
       + (size_t)((((k >> 3) & 3) * 16 + (n & 15)) * 8 + (k & 7));
}

// =====================================================================
// prep kernel: M = Wq*Wk^T (packed bf16), Wv packed bf16, u=Wq@bk, w=Wk@bq, c=bq.bk
// =====================================================================
__global__ __launch_bounds__(256) void vortex_prep(
    const float* __restrict__ Wq, const float* __restrict__ bq,
    const float* __restrict__ Wk, const float* __restrict__ bk,
    const float* __restrict__ Wv,
    short* __restrict__ Mp, short* __restrict__ Vp,
    float* __restrict__ uvec, float* __restrict__ wvec, float* __restrict__ cval)
{
  const int blk = blockIdx.x, tid = threadIdx.x;
  const int wv = tid >> 6, lane = tid & 63;
  if (blk < 256){
    // 1024 tiles of 16x16, one per wave: M[d1][d2] = sum_j Wq[d1][j]*Wk[d2][j]
    const int tile = blk * 4 + wv, ti = tile >> 5, tj = tile & 31;
    const int r = lane & 15, g = lane >> 4;
    f32x4 acc = {0.f, 0.f, 0.f, 0.f};
    for (int k0 = 0; k0 < 512; k0 += 32){
      const float* ap = Wq + (ti*16 + r)*512 + k0 + g*8;
      const float* bp = Wk + (tj*16 + r)*512 + k0 + g*8;
      f32x4 a0 = *(const f32x4*)ap, a1 = *(const f32x4*)(ap+4);
      f32x4 b0 = *(const f32x4*)bp, b1 = *(const f32x4*)(bp+4);
      short8 av, bv8;
      av[0]=f2bf(a0[0]); av[1]=f2bf(a0[1]); av[2]=f2bf(a0[2]); av[3]=f2bf(a0[3]);
      av[4]=f2bf(a1[0]); av[5]=f2bf(a1[1]); av[6]=f2bf(a1[2]); av[7]=f2bf(a1[3]);
      bv8[0]=f2bf(b0[0]); bv8[1]=f2bf(b0[1]); bv8[2]=f2bf(b0[2]); bv8[3]=f2bf(b0[3]);
      bv8[4]=f2bf(b1[0]); bv8[5]=f2bf(b1[1]); bv8[6]=f2bf(b1[2]); bv8[7]=f2bf(b1[3]);
      acc = __builtin_amdgcn_mfma_f32_16x16x32_bf16(av, bv8, acc, 0, 0, 0);
    }
    #pragma unroll
    for (int rr = 0; rr < 4; ++rr){
      int d1 = ti*16 + g*4 + rr, d2 = tj*16 + r;   // C/D: col=lane&15, row=(lane>>4)*4+reg
      Mp[prep_off(d1, d2)] = f2bf(acc[rr]);
    }
  } else if (blk < 320){
    // pack Wv (fp32 row-major) -> bf16 B-ready layout
    int base = ((blk - 256) * 256 + tid) * 16;
    #pragma unroll
    for (int e = 0; e < 16; ++e){
      int idx = base + e;
      Vp[prep_off(idx >> 9, idx & 511)] = f2bf(Wv[idx]);
    }
  } else if (blk < 448){
    // u[d] = Wq[d,:].bk ; w[d] = Wk[d,:].bq  — one wave per d (coalesced rows)
    const int d = (blk - 320) * 4 + wv;
    const float* wqr = Wq + (size_t)d*512 + lane*8;
    const float* wkr = Wk + (size_t)d*512 + lane*8;
    f32x4 q0 = *(const f32x4*)wqr,          q1 = *(const f32x4*)(wqr + 4);
    f32x4 k0 = *(const f32x4*)wkr,          k1 = *(const f32x4*)(wkr + 4);
    f32x4 bk0 = *(const f32x4*)(bk + lane*8), bk1 = *(const f32x4*)(bk + lane*8 + 4);
    f32x4 bq0 = *(const f32x4*)(bq + lane*8), bq1 = *(const f32x4*)(bq + lane*8 + 4);
    float su = wred64(dot8(q0, q1, bk0, bk1));
    float sw = wred64(dot8(k0, k1, bq0, bq1));
    if (lane == 0){ uvec[d] = su; wvec[d] = sw; }
  } else {
    if (wv == 0){
      f32x4 a0 = *(const f32x4*)(bq + lane*8), a1 = *(const f32x4*)(bq + lane*8 + 4);
      f32x4 b0 = *(const f32x4*)(bk + lane*8), b1 = *(const f32x4*)(bk + lane*8 + 4);
      float s = wred64(dot8(a0, a1, b0, b1));
      if (lane == 0) *cval = s;
    }
  }
}

// =====================================================================
// main fused kernel
// =====================================================================
// one 80x256 GEMM pass, weights straight from global (L2-resident packed layout):
// acc[5][2] += X(80x512 bf16 LDS) @ prep[:, p*256 : p*256+256]; wave w owns cols w*32..w*32+31
static __device__ __forceinline__ void gemm_kloop_reg(const char* __restrict__ prep, int p,
                                                      const char* sm, int w, int lane,
                                                      f32x4 (&acc)[5][2])
{
  const int l15 = lane & 15, lg = lane >> 4;
  #pragma unroll
  for (int ks = 0; ks < 16; ++ks){
    const char* bbase = prep + (size_t)((ks*2 + p)*16 + 2*w) * 1024 + lane*16;
    short8 b0 = *(const short8*)(bbase);
    short8 b1 = *(const short8*)(bbase + 1024);
    short8 af[5];
    #pragma unroll
    for (int mf = 0; mf < 5; ++mf){
      const int row = mf*16 + l15;
      af[mf] = *(const short8*)(sm + (row << 10) + (((ks << 6) | (lg << 4)) ^ ((row & 7) << 4)));
    }
    #pragma unroll
    for (int mf = 0; mf < 5; ++mf){
      acc[mf][0] = __builtin_amdgcn_mfma_f32_16x16x32_bf16(af[mf], b0, acc[mf][0], 0,0,0);
      acc[mf][1] = __builtin_amdgcn_mfma_f32_16x16x32_bf16(af[mf], b1, acc[mf][1], 0,0,0);
    }
  }
}

__global__ __launch_bounds__(512, 2) void vortex_main(
    const float* __restrict__ nf, const float* __restrict__ pos,
    const float* __restrict__ bv, const float* __restrict__ Wg, const float* __restrict__ bgp,
    const short* __restrict__ Mp, const short* __restrict__ Vp,
    const float* __restrict__ uvec, const float* __restrict__ wvec, const float* __restrict__ cptr,
    float* __restrict__ out)
{
  __shared__ __align__(16) char sm[SM_TOT];
  const int tid = threadIdx.x;
  const int w = tid >> 6, lane = tid & 63;
  const int l15 = lane & 15, lg = lane >> 4;
  const int wg = blockIdx.x;

  short8 creg;   // this wave's central row (batch w), bf16
  // ---------------- setup: X -> LDS (bf16, swizzled), dots, gate, mask ----------------
  {
    const int col0 = lane * 8;
    f32x4 u0 = *(const f32x4*)(uvec + col0), u1 = *(const f32x4*)(uvec + col0 + 4);
    f32x4 v0 = *(const f32x4*)(wvec + col0), v1 = *(const f32x4*)(wvec + col0 + 4);
    f32x4 g0 = *(const f32x4*)(Wg   + col0), g1 = *(const f32x4*)(Wg   + col0 + 4);
    const size_t gb = ((size_t)wg*8 + w) * 9 * 512;
    for (int rl = 0; rl < 9; ++rl){
      f32x4 n0 = *(const f32x4*)(nf + gb + rl*512 + col0);
      f32x4 n1 = *(const f32x4*)(nf + gb + rl*512 + col0 + 4);
      f32x4 p0 = *(const f32x4*)(pos + rl*512 + col0);
      f32x4 p1 = *(const f32x4*)(pos + rl*512 + col0 + 4);
      f32x4 x0 = n0 + p0, x1 = n1 + p1;
      short8 xb;
      xb[0]=f2bf(x0[0]); xb[1]=f2bf(x0[1]); xb[2]=f2bf(x0[2]); xb[3]=f2bf(x0[3]);
      xb[4]=f2bf(x1[0]); xb[5]=f2bf(x1[1]); xb[6]=f2bf(x1[2]); xb[7]=f2bf(x1[3]);
      const int row = w*9 + rl;
      *(short8*)(sm + (row << 10) + ((lane << 4) ^ ((row & 7) << 4))) = xb;
      float pa = wred64(dot8(x0, x1, u0, u1));
      float pb = wred64(dot8(x0, x1, v0, v1));
      if (lane == 0){
        ((float*)(sm + SM_A))[row] = pa;
        ((float*)(sm + SM_B))[row] = pb;
      }
      if (rl == 8){
        short8 cb;
        cb[0]=f2bf(n0[0]); cb[1]=f2bf(n0[1]); cb[2]=f2bf(n0[2]); cb[3]=f2bf(n0[3]);
        cb[4]=f2bf(n1[0]); cb[5]=f2bf(n1[1]); cb[6]=f2bf(n1[2]); cb[7]=f2bf(n1[3]);
        creg = cb;
        float pg = wred64(dot8(n0, n1, g0, g1));
        if (lane == 0){
          float z = pg + bgp[0];
          ((float*)(sm + SM_G))[w] = 1.f / (1.f + __expf(-z));
        }
      }
    }
    { // zero pad row (72+w)
      const int row = 72 + w;
      short8 z = {0,0,0,0,0,0,0,0};
      *(short8*)(sm + (row << 10) + ((lane << 4) ^ ((row & 7) << 4))) = z;
    }
    for (int t = tid; t < 1040; t += 512){   // zero BigW (80*208 B)
      f32x4 z = {0.f,0.f,0.f,0.f};
      *(f32x4*)(sm + SM_BW + t*16) = z;
    }
    if (tid < 81){
      int n = tid / 9, m = tid - (tid/9)*9;
      bool edge = ((n%3)==0 && (m%3)==1) || ((n%3)==1 && (m%3)==0)
               || (n==2 && m==5) || (n==5 && m==2);
      float mv = (n==8 || m==8) ? 1.5f : (edge ? 2.0f : 1.0f);
      ((float*)(sm + SM_MASK))[tid] = mv;
    }
  }
  __syncthreads();

  // score tile assignment (13 tiles covering block-diag of 80x80)
  const int mi0 = (w + 1) / 3,  nj0 = w - 2*mi0;
  const int mi1 = (w + 9) / 3,  nj1 = (w + 8) - 2*mi1;

  f32x4 sacc0 = {0.f,0.f,0.f,0.f}, sacc1 = {0.f,0.f,0.f,0.f};

  // ---------------- G1: t = X@M (2 passes of 256 cols) + score MFMA ----------------
  for (int p = 0; p < 2; ++p){
    f32x4 tacc[5][2];
    #pragma unroll
    for (int mf = 0; mf < 5; ++mf){
      tacc[mf][0] = (f32x4){0.f,0.f,0.f,0.f};
      tacc[mf][1] = (f32x4){0.f,0.f,0.f,0.f};
    }
    gemm_kloop_reg((const char*)Mp, p, sm, w, lane, tacc);
    // write T (row-major [80][256] bf16, swizzled)
    #pragma unroll
    for (int mf = 0; mf < 5; ++mf)
      #pragma unroll
      for (int nfi = 0; nfi < 2; ++nfi){
        const int col = w*32 + nfi*16 + l15;
        #pragma unroll
        for (int r = 0; r < 4; ++r){
          const int row = mf*16 + lg*4 + r;
          *(short*)(sm + SM_U + (row << 9) + ((col*2) ^ ((row & 7) << 4))) = f2bf(tacc[mf][nfi][r]);
        }
      }
    __syncthreads();
    // S^T tiles: D[m][n] = sum_d2 X[m][d2] * T[n][d2]
    #pragma unroll
    for (int ks = 0; ks < 8; ++ks){
      const int ar = mi0*16 + l15;
      short8 a = *(const short8*)(sm + (ar<<10) + (((p<<9)|(ks<<6)|(lg<<4)) ^ ((ar&7)<<4)));
      const int br = nj0*16 + l15;
      short8 b = *(const short8*)(sm + SM_U + (br<<9) + (((ks<<6)|(lg<<4)) ^ ((br&7)<<4)));
      sacc0 = __builtin_amdgcn_mfma_f32_16x16x32_bf16(a, b, sacc0, 0,0,0);
    }
    if (w < 5){
      #pragma unroll
      for (int ks = 0; ks < 8; ++ks){
        const int ar = mi1*16 + l15;
        short8 a = *(const short8*)(sm + (ar<<10) + (((p<<9)|(ks<<6)|(lg<<4)) ^ ((ar&7)<<4)));
        const int br = nj1*16 + l15;
        short8 b = *(const short8*)(sm + SM_U + (br<<9) + (((ks<<6)|(lg<<4)) ^ ((br&7)<<4)));
        sacc1 = __builtin_amdgcn_mfma_f32_16x16x32_bf16(a, b, sacc1, 0,0,0);
      }
    }
    __syncthreads();
  }

  // ---------------- extract block-diag scores ----------------
  {
    #pragma unroll
    for (int r = 0; r < 4; ++r){
      const int m = mi0*16 + lg*4 + r, n = nj0*16 + l15;
      if (m < 72 && n < 72){
        const int bm = (m*57)>>9, bn = (n*57)>>9;
        if (bm == bn)
          ((float*)(sm + SM_S))[bm*81 + (n - bn*9)*9 + (m - bm*9)] = sacc0[r];
      }
    }
    if (w < 5){
      #pragma unroll
      for (int r = 0; r < 4; ++r){
        const int m = mi1*16 + lg*4 + r, n = nj1*16 + l15;
        if (m < 72 && n < 72){
          const int bm = (m*57)>>9, bn = (n*57)>>9;
          if (bm == bn)
            ((float*)(sm + SM_S))[bm*81 + (n - bn*9)*9 + (m - bm*9)] = sacc1[r];
        }
      }
    }
  }
  __syncthreads();

  // ---------------- softmax -> BigW (w*(1-g) in diag block, g at col 80+b) ----------------
  if (tid < 72){
    const int b = tid / 9, np = tid - b*9;
    const float g  = ((float*)(sm + SM_G))[b];
    const float an = ((float*)(sm + SM_A))[b*9 + np];
    const float cv = cptr[0];
    const float scl = 0.04419417382415922f;   // 1/sqrt(512)
    float vals[9]; float mx = -1e30f;
    #pragma unroll
    for (int m = 0; m < 9; ++m){
      float s = (((float*)(sm + SM_S))[b*81 + np*9 + m] + an
                 + ((float*)(sm + SM_B))[b*9 + m] + cv)
              * scl * ((float*)(sm + SM_MASK))[np*9 + m];
      vals[m] = s; mx = fmaxf(mx, s);
    }
    float sum = 0.f;
    #pragma unroll
    for (int m = 0; m < 9; ++m){ vals[m] = __expf(vals[m] - mx); sum += vals[m]; }
    const float wsc = (1.f - g) / sum;
    const int rowg = b*9 + np;
    #pragma unroll
    for (int m = 0; m < 9; ++m)
      *(short*)(sm + SM_BW + rowg*208 + (b*9 + m)*2) = f2bf(vals[m]*wsc);
    *(short*)(sm + SM_BW + rowg*208 + (80 + b)*2) = f2bf(g);
  }
  __syncthreads();

  // ---------------- G2: V = X@Wv -> V^T LDS; out = BigW @ V (+ (1-g)*bv) ----------------
  for (int p = 0; p < 2; ++p){
    f32x4 vacc[5][2];
    #pragma unroll
    for (int mf = 0; mf < 5; ++mf){
      vacc[mf][0] = (f32x4){0.f,0.f,0.f,0.f};
      vacc[mf][1] = (f32x4){0.f,0.f,0.f,0.f};
    }
    gemm_kloop_reg((const char*)Vp, p, sm, w, lane, vacc);
    // V^T: [256][104] bf16 (stride 208 B = 13 granules -> conflict-free)
    #pragma unroll
    for (int mf = 0; mf < 5; ++mf)
      #pragma unroll
      for (int nfi = 0; nfi < 2; ++nfi){
        const int d  = w*32 + nfi*16 + l15;      // chunk-local col of V
        const int m0 = mf*16 + lg*4;
        short4v pk;
        pk[0]=f2bf(vacc[mf][nfi][0]); pk[1]=f2bf(vacc[mf][nfi][1]);
        pk[2]=f2bf(vacc[mf][nfi][2]); pk[3]=f2bf(vacc[mf][nfi][3]);
        *(short4v*)(sm + SM_U + d*208 + m0*2) = pk;
      }
    #pragma unroll
    for (int j = 0; j < 8; ++j){                 // central rows 80..87
      const int d = lane*8 + j;
      if ((d >> 8) == p)
        *(short*)(sm + SM_U + (d & 255)*208 + (80 + w)*2) = creg[j];
    }
    if (tid < 256){                              // zero pad cols 88..95 (PV reads k<96)
      f32x4 z = {0.f,0.f,0.f,0.f};
      *(f32x4*)(sm + SM_U + tid*208 + 176) = z;
    }
    __syncthreads();
    // out chunk = BigW(80x96) @ V(96x256)
    f32x4 oacc[5][2];
    #pragma unroll
    for (int mf = 0; mf < 5; ++mf){
      oacc[mf][0] = (f32x4){0.f,0.f,0.f,0.f};
      oacc[mf][1] = (f32x4){0.f,0.f,0.f,0.f};
    }
    #pragma unroll
    for (int ks = 0; ks < 3; ++ks){
      short8 aw[5], bw0, bw1;
      #pragma unroll
      for (int mf = 0; mf < 5; ++mf){
        const int n = mf*16 + l15;
        aw[mf] = *(const short8*)(sm + SM_BW + n*208 + ks*64 + lg*16);
      }
      bw0 = *(const short8*)(sm + SM_U + (w*32      + l15)*208 + ks*64 + lg*16);
      bw1 = *(const short8*)(sm + SM_U + (w*32 + 16 + l15)*208 + ks*64 + lg*16);
      #pragma unroll
      for (int mf = 0; mf < 5; ++mf){
        oacc[mf][0] = __builtin_amdgcn_mfma_f32_16x16x32_bf16(aw[mf], bw0, oacc[mf][0], 0,0,0);
        oacc[mf][1] = __builtin_amdgcn_mfma_f32_16x16x32_bf16(aw[mf], bw1, oacc[mf][1], 0,0,0);
      }
    }
    // epilogue + store
    #pragma unroll
    for (int nfi = 0; nfi < 2; ++nfi){
      const int d = p*256 + w*32 + nfi*16 + l15;
      const float bvd = bv[d];
      #pragma unroll
      for (int mf = 0; mf < 5; ++mf)
        #pragma unroll
        for (int r = 0; r < 4; ++r){
          const int n = mf*16 + lg*4 + r;
          if (n < 72){
            const int b = (n*57)>>9;
            const float g = ((float*)(sm + SM_G))[b];
            out[((size_t)wg*72 + n)*512 + d] = oacc[mf][nfi][r] + (1.f - g)*bvd;
          }
        }
    }
    __syncthreads();
  }
}

// =====================================================================
extern "C" void kernel_launch(void* const* d_in, const int* in_sizes, int n_in,
                              void* d_out, int out_size, void* d_ws, size_t ws_size,
                              hipStream_t stream)
{
  const float* nf  = (const float*)d_in[0];
  const float* pos = (const float*)d_in[1];
  const float* Wq  = (const float*)d_in[2];
  const float* bq  = (const float*)d_in[3];
  const float* Wk  = (const float*)d_in[4];
  const float* bk  = (const float*)d_in[5];
  const float* Wv  = (const float*)d_in[6];
  const float* bv  = (const float*)d_in[7];
  const float* Wg  = (const float*)d_in[8];
  const float* bg  = (const float*)d_in[9];
  float* out = (float*)d_out;
  char* ws = (char*)d_ws;
  // ws: Mprep 512K | Wvprep 512K | u 2K | w 2K | c 4B   (needs ~1.004 MB)
  short* Mp   = (short*)(ws);
  short* Vp   = (short*)(ws + 524288);
  float* uvec = (float*)(ws + 1048576);
  float* wvec = (float*)(ws + 1050624);
  float* cval = (float*)(ws + 1052672);
  if (ws_size < 1052676) return;

  const int B = in_sizes[0] / (9 * 512);
  vortex_prep<<<449, 256, 0, stream>>>(Wq, bq, Wk, bk, Wv, Mp, Vp, uvec, wvec, cval);
  vortex_main<<<B/8, 512, 0, stream>>>(nf, pos, bv, Wg, bg, Mp, Vp, uvec, wvec, cval, out);
}